// Round 8
// baseline (468.702 us; speedup 1.0000x reference)
//
#include <hip/hip_runtime.h>

// Bidirectional LSTM, B=256, T=1024, V=6, D=64, U=64; out = last-step
// concat(h_f, h_b) @ Wd + bd, shape (B,1).
// Reductions: backward dir = ONE step from h0=0 (Wr_b dead); V=6 -> xproj is
// a 6-entry per-column table; mask = 6-bit scalar.
// History: R12 296us / R13-15 reg-resident 400-460 (RA spill) / R16 360 /
// R17 300 / R18 (2 batches, 1 lane) 495 / R19 (sel6 regs, min DS) 352.
// R19 post-mortem: DS-count model dead (44->14 DS made it SLOWER than R12).
//   Prefetched LDS reads are latency-hidden (free); sel6 cndmask chains are
//   serial issue on the critical path. Revert to R12's LDS proj prefetch.
// R18 post-mortem: batch-pair amortization DID cut per-batch step 700->580,
//   but software-interleaved in one lane + half the grid = net loss.
// R20: R12's proven step VERBATIM x 2 independent 4-wave groups per block
//   (512 thr): waves 0-3 = batch bP, waves 4-7 = batch bQ. Shared weights +
//   proj table; per-group s_hh/tokens; one block barrier/step. The HW
//   scheduler (2 waves/SIMD) fills one group's latency stalls (h LDS RT,
//   act dep chain, barrier drift) with the other group's VALU issue (m114).
//   Grid 128 x 512. launch_bounds(512,2): VGPR cap 256, demand ~80.

constexpr int kB = 256;
constexpr int kT = 1024;
constexpr int kV = 6;
constexpr int kD = 64;
constexpr int kU = 64;
constexpr int kG = 256; // 4*U gate columns

#define LOG2E 1.44269504f

typedef _Float16 v2h __attribute__((ext_vector_type(2)));

template <int CTRL>
__device__ __forceinline__ float dppf(float x) {
    return __int_as_float(
        __builtin_amdgcn_mov_dpp(__float_as_int(x), CTRL, 0xF, 0xF, true));
}
constexpr int kXor1 = 0xB1; // quad_perm(1,0,3,2)
constexpr int kXor2 = 0x4E; // quad_perm(2,3,0,1)
constexpr int kBc0 = 0x00, kBc1 = 0x55, kBc2 = 0xAA, kBc3 = 0xFF;

__device__ __forceinline__ float fast_rcp(float x) { return __builtin_amdgcn_rcpf(x); }
__device__ __forceinline__ float exp2_f(float x)   { return __builtin_amdgcn_exp2f(x); }
__device__ __forceinline__ float tanh_f(float z) { return 2.0f * fast_rcp(1.0f + exp2_f(-2.0f * LOG2E * z)) - 1.0f; }

__device__ __forceinline__ v2h as_v2h(float x) { return __builtin_bit_cast(v2h, x); }

__global__ __launch_bounds__(512, 2) void bilstm_last_kernel(
    const int*   __restrict__ tokens, // (B,T)
    const float* __restrict__ emb,    // (6,64)
    const float* __restrict__ Wk_f,   // (64,256)
    const float* __restrict__ Wr_f,   // (64,256)
    const float* __restrict__ b_f,    // (256)
    const float* __restrict__ Wk_b,   // (64,256)
    const float* __restrict__ b_b,    // (256)
    const float* __restrict__ Wd,     // (128)
    const float* __restrict__ bd,     // (1)
    float*       __restrict__ out)    // (B)
{
    __shared__ float s_emb[kV * kD];
    __shared__ float __align__(16) s_projP[kV * kG];   // [v][idx256], shared by groups
    __shared__ int   __align__(16) s_tok[2][kT];       // [group][t]
    __shared__ _Float16 __align__(16) s_hh[2][2][kU];  // [buf][group][unit]
    __shared__ float s_red[2][4];

    const int b0  = blockIdx.x * 2;
    const int tid = threadIdx.x;     // 0..511
    const int wv  = tid >> 6;        // wave 0..7
    const int q   = wv >> 2;         // batch group 0/1
    const int w   = wv & 3;          // wave-in-group 0..3
    const int l   = tid & 63;        // lane
    const int s   = l & 3;           // gate AND h-slice (0=i,1=f,2=g,3=o)
    const int k   = l >> 2;          // quad id 0..15
    const int u   = w * 16 + k;      // unit owned by this quad
    const int col = s * kU + u;      // owned gate column in (.,256) matrices
    const int idx = w * kU + l;      // 0..255, same col <-> same idx across groups

    // ---- stage emb + tokens (both batches contiguous: bQ = bP+1) ----
    for (int i = tid; i < kV * kD; i += 512) s_emb[i] = emb[i];
    ((int4*)s_tok)[tid] = ((const int4*)(tokens + b0 * kT))[tid]; // 512*16B = 8KB
    if (tid < 2 * 2 * kU) ((_Float16*)s_hh)[tid] = (_Float16)0.f;
    __syncthreads();   // emb + tokens visible

    // ---- 6-bit mask, scalarized (emb-based, batch-independent) ----
    unsigned int mbv = 0;
#pragma unroll
    for (int v = 0; v < kV; ++v) {
        const unsigned long long bb = __ballot(s_emb[v * kD + l] != 0.0f);
        mbv |= (bb != 0ull) ? (1u << v) : 0u;
    }
    const unsigned int smb = __builtin_amdgcn_readfirstlane(mbv);

    const int tokL = __builtin_amdgcn_readfirstlane(s_tok[q][kT - 1]);

    // per-lane activation constants: gate s==2 is tanh, others sigmoid
    const bool  isg    = (s == 2);
    const float aScale = isg ? -2.0f * LOG2E : -LOG2E;
    const float aMul   = isg ? 2.0f : 1.0f;
    const float aAdd   = isg ? -1.0f : 0.0f;

    // ---- proj for own column (6 tokens, group 0 stores shared table) and
    //      the backward column at THIS group's last token ----
    float ab;
    {
        float afv[kV];
        const float bf = b_f[col];
#pragma unroll
        for (int v = 0; v < kV; ++v) afv[v] = bf;
        ab = b_b[col];
#pragma unroll 4
        for (int d = 0; d < kD; ++d) {
            const float wkf = Wk_f[d * kG + col];
            const float wkb = Wk_b[d * kG + col];
            afv[0] = fmaf(s_emb[0 * kD + d], wkf, afv[0]);
            afv[1] = fmaf(s_emb[1 * kD + d], wkf, afv[1]);
            afv[2] = fmaf(s_emb[2 * kD + d], wkf, afv[2]);
            afv[3] = fmaf(s_emb[3 * kD + d], wkf, afv[3]);
            afv[4] = fmaf(s_emb[4 * kD + d], wkf, afv[4]);
            afv[5] = fmaf(s_emb[5 * kD + d], wkf, afv[5]);
            ab     = fmaf(s_emb[tokL * kD + d], wkb, ab);
        }
        if (q == 0) {
#pragma unroll
            for (int v = 0; v < kV; ++v) s_projP[v * kG + idx] = afv[v];
        }
    }

    // ---- backward single step via quad DPP (c0=0 -> f dead) ----
    float hb_val;
    {
        const float e = exp2_f(ab * aScale);
        const float r = fast_rcp(1.0f + e);
        const float a = fmaf(r, aMul, aAdd);
        const float cb = dppf<kBc0>(a) * dppf<kBc2>(a);
        const float hb = dppf<kBc3>(a) * tanh_f(cb);
        hb_val = ((smb >> tokL) & 1) ? hb : 0.0f;
    }

    // ---- recurrent weights: K-slice s of own unit's 4 gate columns ----
#define DECLH(g, p)                                                           \
    v2h wh##g##_##p;                                                          \
    wh##g##_##p.x = (_Float16)Wr_f[(16 * s + 2 * (p) + 0) * kG + ((g) * 64 + u)]; \
    wh##g##_##p.y = (_Float16)Wr_f[(16 * s + 2 * (p) + 1) * kG + ((g) * 64 + u)];
    DECLH(0,0) DECLH(0,1) DECLH(0,2) DECLH(0,3) DECLH(0,4) DECLH(0,5) DECLH(0,6) DECLH(0,7)
    DECLH(1,0) DECLH(1,1) DECLH(1,2) DECLH(1,3) DECLH(1,4) DECLH(1,5) DECLH(1,6) DECLH(1,7)
    DECLH(2,0) DECLH(2,1) DECLH(2,2) DECLH(2,3) DECLH(2,4) DECLH(2,5) DECLH(2,6) DECLH(2,7)
    DECLH(3,0) DECLH(3,1) DECLH(3,2) DECLH(3,3) DECLH(3,4) DECLH(3,5) DECLH(3,6) DECLH(3,7)
#undef DECLH

    float c = 0.0f, hreg = 0.0f;
    __syncthreads();   // projP visible (h buffers already zeroed pre-mask)

    // ---- scalar token pipeline, depth 2 (R12-proven: prefetch through LDS) ----
    int stok0 = __builtin_amdgcn_readfirstlane(s_tok[q][0]);
    float zcur = s_projP[stok0 * kG + idx];
    int   mskc = (smb >> stok0) & 1;
    int   stokA = __builtin_amdgcn_readfirstlane(s_tok[q][1]);

    // per gate: 8 dot2 in 2 chains of depth 4 over the 16-unit slice
#define DOTG(g)                                                               \
        float pa##g = __builtin_amdgcn_fdot2(H0, wh##g##_0, 0.0f, false);     \
        float pb##g = __builtin_amdgcn_fdot2(H1, wh##g##_1, 0.0f, false);     \
        pa##g = __builtin_amdgcn_fdot2(H2, wh##g##_2, pa##g, false);          \
        pb##g = __builtin_amdgcn_fdot2(H3, wh##g##_3, pb##g, false);          \
        pa##g = __builtin_amdgcn_fdot2(H4, wh##g##_4, pa##g, false);          \
        pb##g = __builtin_amdgcn_fdot2(H5, wh##g##_5, pb##g, false);          \
        pa##g = __builtin_amdgcn_fdot2(H6, wh##g##_6, pa##g, false);          \
        pb##g = __builtin_amdgcn_fdot2(H7, wh##g##_7, pb##g, false);          \
        float p##g = pa##g + pb##g;

    // h-buffer safety: step t reads s_hh[RP][q] before its barrier (reads
    // drain at the barrier's lgkmcnt(0)); RP is rewritten only after that
    // barrier. Double-buffer + 1 block barrier/step is safe for both groups.
#define STEP(RP, WP, TT)                                                      \
    {                                                                         \
        /* h reads FIRST; slice s = 16 halves = 32B = 2x b128; the 4 slices   \
           cover all 32 banks exactly once -> conflict-free */                \
        const float4* hp = (const float4*)s_hh[RP][q];                        \
        const float4 hv0 = hp[s * 2 + 0];                                     \
        const float4 hv1 = hp[s * 2 + 1];                                     \
        /* prefetches behind h in the queue; consumed next step */            \
        const int   vtokB = s_tok[q][((TT) + 2) & (kT - 1)];                  \
        const float znext = s_projP[stokA * kG + idx];                        \
        const int   mskn  = (int)((smb >> stokA) & 1);                        \
        const v2h H0 = as_v2h(hv0.x), H1 = as_v2h(hv0.y);                     \
        const v2h H2 = as_v2h(hv0.z), H3 = as_v2h(hv0.w);                     \
        const v2h H4 = as_v2h(hv1.x), H5 = as_v2h(hv1.y);                     \
        const v2h H6 = as_v2h(hv1.z), H7 = as_v2h(hv1.w);                     \
        DOTG(0) DOTG(1) DOTG(2) DOTG(3)                                       \
        /* transpose-butterfly: slice-sums -> own-gate z (R12-verified) */    \
        p0 += dppf<kXor1>(p0); p1 += dppf<kXor1>(p1);                         \
        p2 += dppf<kXor1>(p2); p3 += dppf<kXor1>(p3);                         \
        float X = (s & 1) ? p1 : p0;                                          \
        float Y = (s & 1) ? p3 : p2;                                          \
        X += dppf<kXor2>(X); Y += dppf<kXor2>(Y);                             \
        const float z = ((s & 2) ? Y : X) + zcur;                             \
        /* one activation per lane (own gate) */                              \
        const float e = exp2_f(z * aScale);                                   \
        const float r = fast_rcp(1.0f + e);                                   \
        const float a = fmaf(r, aMul, aAdd);                                  \
        /* quad broadcasts: gate g lives in lane g of the quad */             \
        const float ai = dppf<kBc0>(a);                                       \
        const float af = dppf<kBc1>(a);                                       \
        const float ag = dppf<kBc2>(a);                                       \
        const float ao = dppf<kBc3>(a);                                       \
        const float cn = fmaf(af, c, ai * ag);                                \
        const float hn = ao * tanh_f(cn);                                     \
        if (mskc) { c = cn; hreg = hn; }   /* uniform branch */               \
        if (s == 0) s_hh[WP][q][u] = (_Float16)hreg;                          \
        __syncthreads();                                                      \
        zcur = znext; mskc = mskn;                                            \
        stokA = __builtin_amdgcn_readfirstlane(vtokB);                        \
    }

#pragma unroll 1
    for (int t = 0; t < kT; t += 2) {
        STEP(0, 1, t)
        STEP(1, 0, t + 1)
    }
#undef STEP
#undef DOTG

    // ---- epilogue: quad lane s==0 holds exact f32 h_f[u], h_b[u] ----
    {
        float v = (s == 0) ? (hreg * Wd[u] + hb_val * Wd[kU + u]) : 0.0f;
#pragma unroll
        for (int off = 32; off > 0; off >>= 1) v += __shfl_down(v, off, 64);
        if (l == 0) s_red[q][w] = v;
    }
    __syncthreads();
    if (tid == 0) {
        out[b0]     = (s_red[0][0] + s_red[0][1]) + (s_red[0][2] + s_red[0][3]) + bd[0];
        out[b0 + 1] = (s_red[1][0] + s_red[1][1]) + (s_red[1][2] + s_red[1][3]) + bd[0];
    }
}

extern "C" void kernel_launch(void* const* d_in, const int* in_sizes, int n_in,
                              void* d_out, int out_size, void* d_ws, size_t ws_size,
                              hipStream_t stream) {
    const int*   tokens = (const int*)d_in[0];
    const float* emb    = (const float*)d_in[1];
    const float* Wk_f   = (const float*)d_in[2];
    const float* Wr_f   = (const float*)d_in[3];
    const float* b_f    = (const float*)d_in[4];
    const float* Wk_b   = (const float*)d_in[5];
    // d_in[6] = Wr_b: unused (backward runs one step from h0=0)
    const float* b_b    = (const float*)d_in[7];
    const float* Wd     = (const float*)d_in[8];
    const float* bd     = (const float*)d_in[9];
    float* out = (float*)d_out;

    bilstm_last_kernel<<<kB / 2, 512, 0, stream>>>(
        tokens, emb, Wk_f, Wr_f, b_f, Wk_b, b_b, Wd, bd, out);
}